// Round 1
// baseline (364.375 us; speedup 1.0000x reference)
//
#include <hip/hip_runtime.h>

typedef _Float16 half8 __attribute__((ext_vector_type(8)));
typedef float f32x4 __attribute__((ext_vector_type(4)));

#define NB 4
#define NC 128
#define NN 4096

// ---------------------------------------------------------------------------
// Kernel 1: QKV projection (1x1 conv). fp32 VALU compute, fp16 outputs.
// Q,K stored [B,N,C]; V stored transposed [B,C,N] so PV B-frags are contiguous.
// grid 256 (= B * N/64), block 256. Wave-uniform output-channel chunk so the
// weight reads become s_load_dwordx4.
// ---------------------------------------------------------------------------
__global__ __launch_bounds__(256) void qkv_proj_kernel(
    const float* __restrict__ x,
    const float* __restrict__ wq, const float* __restrict__ bq,
    const float* __restrict__ wk, const float* __restrict__ bk,
    const float* __restrict__ wv, const float* __restrict__ bv,
    _Float16* __restrict__ Qb, _Float16* __restrict__ Kb, _Float16* __restrict__ Vt)
{
    const int tid = threadIdx.x;
    const int b   = blockIdx.x >> 6;
    const int n0  = (blockIdx.x & 63) << 6;

    __shared__ float xs[128][64];   // [c][pixel], stride 64 floats -> 2-way free

    #pragma unroll
    for (int kk = 0; kk < 8; ++kk) {
        int g  = kk * 256 + tid;
        int c  = g >> 4;
        int n4 = (g & 15) << 2;
        *(float4*)(&xs[c][n4]) = *(const float4*)(x + (size_t)(b * NC + c) * NN + n0 + n4);
    }
    __syncthreads();

    const int lane  = tid & 63;                                   // pixel
    const int obase = __builtin_amdgcn_readfirstlane(tid >> 6) * 32; // out-chan chunk (wave-uniform)

    #pragma unroll 1
    for (int mat = 0; mat < 3; ++mat) {
        const float* __restrict__ W  = (mat == 0) ? wq : ((mat == 1) ? wk : wv);
        const float* __restrict__ bi = (mat == 0) ? bq : ((mat == 1) ? bk : bv);

        float acc[32];
        #pragma unroll
        for (int i = 0; i < 32; ++i) acc[i] = 0.f;

        #pragma unroll 2
        for (int c4 = 0; c4 < 32; ++c4) {
            float x0 = xs[c4*4+0][lane];
            float x1 = xs[c4*4+1][lane];
            float x2 = xs[c4*4+2][lane];
            float x3 = xs[c4*4+3][lane];
            #pragma unroll
            for (int i = 0; i < 32; ++i) {
                float4 w4 = *(const float4*)(W + (size_t)(obase + i) * NC + c4*4); // uniform -> s_load
                acc[i] = fmaf(w4.w, x3, fmaf(w4.z, x2, fmaf(w4.y, x1, fmaf(w4.x, x0, acc[i]))));
            }
        }
        #pragma unroll
        for (int i = 0; i < 32; ++i) acc[i] += bi[obase + i];

        if (mat < 2) {
            _Float16* dst = (mat == 0) ? Qb : Kb;
            _Float16* p = dst + (size_t)(b * NN + n0 + lane) * NC + obase;
            #pragma unroll
            for (int j = 0; j < 4; ++j) {
                half8 hv;
                #pragma unroll
                for (int e = 0; e < 8; ++e) hv[e] = (_Float16)acc[j*8 + e];
                *(half8*)(p + j*8) = hv;
            }
        } else {
            #pragma unroll
            for (int i = 0; i < 32; ++i)
                Vt[(size_t)(b * NC + obase + i) * NN + n0 + lane] = (_Float16)acc[i]; // coalesced over lanes
        }
    }
}

// ---------------------------------------------------------------------------
// Kernel 2: fused flash attention, fp16 MFMA 16x16x32, fp32 accum.
// grid 256 (XCD-swizzled so each XCD sees one batch), block 256 = 4 waves,
// each wave owns 16 query rows; 64 iterations over 64-row KV tiles.
// LDS: K tile [64][128] + Vt tile [128][64] (XOR-swizzled), per-wave P buffer.
// ---------------------------------------------------------------------------
__global__ __launch_bounds__(256, 1) void attn_kernel(
    const _Float16* __restrict__ Qb, const _Float16* __restrict__ Kb,
    const _Float16* __restrict__ Vt, float* __restrict__ out)
{
    const int tid = threadIdx.x;
    const int bid = blockIdx.x;
    // XCD swizzle: hardware round-robins bid%8 across XCDs; give each XCD one batch
    const int b  = (bid & 7) >> 1;
    const int qt = ((bid >> 3) << 1) | (bid & 1);
    const int n0 = qt << 6;

    const int lane = tid & 63;
    const int wave = __builtin_amdgcn_readfirstlane(tid >> 6);
    const int l15  = lane & 15;
    const int lg   = lane >> 4;

    // [0,16384): K tile [64][128] half, swizzled
    // [16384,32768): V tile [128][64] half (c-major), swizzled
    // [32768,40960): P buffers, 2KB per wave [16][64] half, swizzled
    __shared__ __align__(16) unsigned char smem[40960];

    // ---- Q fragments (A operand): row = lane&15, k = (lane>>4)*8 + j ----
    half8 aq[4];
    {
        const _Float16* qrow = Qb + (size_t)(b * NN + n0 + wave * 16 + l15) * NC + lg * 8;
        #pragma unroll
        for (int kc = 0; kc < 4; ++kc) aq[kc] = *(const half8*)(qrow + kc * 32);
    }

    // ---- staging offsets (per-thread 4 chunks of K + 4 of V, 16B each) ----
    int kdst[4], vdst[4], ksrc[4], vsrc[4];
    #pragma unroll
    for (int kk = 0; kk < 4; ++kk) {
        int g  = kk * 256 + tid;
        int r  = g >> 4, cb = g & 15;
        kdst[kk] = (r * 256 + cb * 16) ^ ((r & 7) << 4);
        ksrc[kk] = r * NC + cb * 8;
        int c  = g >> 3, cb2 = g & 7;
        vdst[kk] = 16384 + ((c * 128 + cb2 * 16) ^ ((c & 7) << 4));
        vsrc[kk] = c * NN + cb2 * 8;
    }
    const _Float16* Kbase = Kb + (size_t)b * NN * NC;
    const _Float16* Vbase = Vt + (size_t)b * NC * NN;

    // ---- fragment read offsets (swizzled byte addresses) ----
    int koff[4][4];
    #pragma unroll
    for (int ct = 0; ct < 4; ++ct) {
        int mr = ct * 16 + l15;
        #pragma unroll
        for (int kc = 0; kc < 4; ++kc)
            koff[ct][kc] = (mr * 256 + kc * 64 + lg * 16) ^ ((mr & 7) << 4);
    }
    int voff[8][2];
    #pragma unroll
    for (int ct2 = 0; ct2 < 8; ++ct2) {
        int c = ct2 * 16 + l15;
        #pragma unroll
        for (int kc2 = 0; kc2 < 2; ++kc2)
            voff[ct2][kc2] = 16384 + ((c * 128 + kc2 * 64 + lg * 16) ^ ((c & 7) << 4));
    }
    int paoff[2];
    #pragma unroll
    for (int kc2 = 0; kc2 < 2; ++kc2)
        paoff[kc2] = 32768 + wave * 2048 + ((l15 * 128 + kc2 * 64 + lg * 16) ^ ((l15 & 7) << 4));
    int pwoff[4][4];
    #pragma unroll
    for (int reg = 0; reg < 4; ++reg) {
        int row = lg * 4 + reg;
        #pragma unroll
        for (int ct = 0; ct < 4; ++ct)
            pwoff[reg][ct] = 32768 + wave * 2048 + ((row * 128 + ct * 32 + l15 * 2) ^ ((row & 7) << 4));
    }

    const f32x4 Z4 = {0.f, 0.f, 0.f, 0.f};
    float m_r[4], l_r[4];
    f32x4 o[8];
    #pragma unroll
    for (int r = 0; r < 4; ++r) { m_r[r] = -3.0e38f; l_r[r] = 0.f; }
    #pragma unroll
    for (int i = 0; i < 8; ++i) o[i] = Z4;

    // prologue: prefetch tile 0 into registers
    uint4 kreg[4], vreg[4];
    #pragma unroll
    for (int kk = 0; kk < 4; ++kk) {
        kreg[kk] = *(const uint4*)(Kbase + ksrc[kk]);
        vreg[kk] = *(const uint4*)(Vbase + vsrc[kk]);
    }

    for (int it = 0; it < 64; ++it) {
        __syncthreads();                       // previous tile's reads done
        #pragma unroll
        for (int kk = 0; kk < 4; ++kk) {
            *(uint4*)(smem + kdst[kk]) = kreg[kk];
            *(uint4*)(smem + vdst[kk]) = vreg[kk];
        }
        __syncthreads();                       // tile visible
        if (it < 63) {                         // prefetch next tile (latency hides under compute)
            int m0 = (it + 1) << 6;
            #pragma unroll
            for (int kk = 0; kk < 4; ++kk) {
                kreg[kk] = *(const uint4*)(Kbase + (size_t)m0 * NC + ksrc[kk]);
                vreg[kk] = *(const uint4*)(Vbase + m0 + vsrc[kk]);
            }
        }

        // ---- S = Q K^T  (wave's 16 rows x 64 kv cols) ----
        f32x4 s[4];
        #pragma unroll
        for (int ct = 0; ct < 4; ++ct) s[ct] = Z4;
        #pragma unroll
        for (int kc = 0; kc < 4; ++kc) {
            half8 a = aq[kc];
            #pragma unroll
            for (int ct = 0; ct < 4; ++ct) {
                half8 bk8 = *(const half8*)(smem + koff[ct][kc]);
                s[ct] = __builtin_amdgcn_mfma_f32_16x16x32_f16(a, bk8, s[ct], 0, 0, 0);
            }
        }

        // ---- online softmax; C/D layout: row=(lane>>4)*4+reg, col=lane&15 ----
        __asm__ volatile("" ::: "memory");     // fence: order P writes after prior P reads
        #pragma unroll
        for (int reg = 0; reg < 4; ++reg) {
            float tmax = fmaxf(fmaxf(s[0][reg], s[1][reg]), fmaxf(s[2][reg], s[3][reg]));
            #pragma unroll
            for (int off = 1; off < 16; off <<= 1)
                tmax = fmaxf(tmax, __shfl_xor(tmax, off, 64));
            float mnew = fmaxf(m_r[reg], tmax);
            float sc   = __expf(m_r[reg] - mnew);   // first iter: exp(-3e38 - m) = 0
            m_r[reg]   = mnew;
            float psum = 0.f;
            #pragma unroll
            for (int ct = 0; ct < 4; ++ct) {
                float p = __expf(s[ct][reg] - mnew);
                psum += p;
                *(_Float16*)(smem + pwoff[reg][ct]) = (_Float16)p;  // P -> LDS (wave-private)
            }
            #pragma unroll
            for (int off = 1; off < 16; off <<= 1)
                psum += __shfl_xor(psum, off, 64);
            l_r[reg] = l_r[reg] * sc + psum;
            #pragma unroll
            for (int ct2 = 0; ct2 < 8; ++ct2) o[ct2][reg] *= sc;
        }
        __asm__ volatile("" ::: "memory");     // fence: P writes before P reads below

        // ---- O += P V  (A = P from LDS transpose, B = V c-major tile) ----
        #pragma unroll
        for (int kc2 = 0; kc2 < 2; ++kc2) {
            half8 pa = *(const half8*)(smem + paoff[kc2]);
            #pragma unroll
            for (int ct2 = 0; ct2 < 8; ++ct2) {
                half8 bv8 = *(const half8*)(smem + voff[ct2][kc2]);
                o[ct2] = __builtin_amdgcn_mfma_f32_16x16x32_f16(pa, bv8, o[ct2], 0, 0, 0);
            }
        }
    }

    // ---- epilogue: out[b][c][n] = O / l ----
    float inv[4];
    #pragma unroll
    for (int r = 0; r < 4; ++r) inv[r] = 1.f / l_r[r];
    #pragma unroll
    for (int ct2 = 0; ct2 < 8; ++ct2) {
        int c = ct2 * 16 + l15;
        #pragma unroll
        for (int reg = 0; reg < 4; ++reg) {
            int n = n0 + wave * 16 + lg * 4 + reg;
            out[(size_t)(b * NC + c) * NN + n] = o[ct2][reg] * inv[reg];
        }
    }
}

extern "C" void kernel_launch(void* const* d_in, const int* in_sizes, int n_in,
                              void* d_out, int out_size, void* d_ws, size_t ws_size,
                              hipStream_t stream)
{
    const float* x  = (const float*)d_in[0];
    const float* wq = (const float*)d_in[1];
    const float* bq = (const float*)d_in[2];
    const float* wk = (const float*)d_in[3];
    const float* bk = (const float*)d_in[4];
    const float* wv = (const float*)d_in[5];
    const float* bv = (const float*)d_in[6];

    _Float16* Qb = (_Float16*)d_ws;                    // [B,N,C] fp16, 4 MB
    _Float16* Kb = Qb + (size_t)NB * NN * NC;          // [B,N,C] fp16, 4 MB
    _Float16* Vb = Kb + (size_t)NB * NN * NC;          // [B,C,N] fp16, 4 MB

    qkv_proj_kernel<<<dim3(256), dim3(256), 0, stream>>>(x, wq, bq, wk, bk, wv, bv, Qb, Kb, Vb);
    attn_kernel<<<dim3(256), dim3(256), 0, stream>>>(Qb, Kb, Vb, (float*)d_out);
}

// Round 2
// 152.318 us; speedup vs baseline: 2.3922x; 2.3922x over previous
//
#include <hip/hip_runtime.h>

typedef _Float16 half8 __attribute__((ext_vector_type(8)));
typedef float f32x4 __attribute__((ext_vector_type(4)));

#define NB 4
#define NC 128
#define NN 4096

// swizzled byte address for x-tile LDS [c][n] f32 (c<128, n<64):
// XOR c-bit3 into bank bit 4 so the 4 lg-groups of a fragment read spread banks
__device__ __forceinline__ int xs_addr(int c, int n) {
    return ((c << 8) + (n << 2)) ^ (((c >> 3) & 1) << 6);
}

// ---------------------------------------------------------------------------
// Kernel 1: QKV projection via fp16 MFMA. grid 256, block 512 (8 waves).
// Each wave: 16 out-chans x 64 pixels per matrix. x fragments built once,
// reused for all 3 weight matrices. Q,K -> [B,N,C] fp16; V -> [B,C,N] fp16.
// ---------------------------------------------------------------------------
__global__ __launch_bounds__(512, 2) void qkv_proj_kernel(
    const float* __restrict__ x,
    const float* __restrict__ wq, const float* __restrict__ bq,
    const float* __restrict__ wk, const float* __restrict__ bk,
    const float* __restrict__ wv, const float* __restrict__ bv,
    _Float16* __restrict__ Qb, _Float16* __restrict__ Kb, _Float16* __restrict__ Vt)
{
    const int tid  = threadIdx.x;
    const int b    = blockIdx.x >> 6;
    const int n0   = (blockIdx.x & 63) << 6;
    const int lane = tid & 63;
    const int wave = __builtin_amdgcn_readfirstlane(tid >> 6);
    const int l15  = lane & 15, lg = lane >> 4;
    const int obase = wave * 16;

    __shared__ __align__(16) unsigned char xsm[32768];   // x tile [128 c][64 n] f32, swizzled

    #pragma unroll
    for (int kk = 0; kk < 4; ++kk) {
        int g = kk * 512 + tid;
        int c = g >> 4, n4 = (g & 15) << 2;
        *(float4*)(xsm + xs_addr(c, n4)) = *(const float4*)(x + (size_t)(b * NC + c) * NN + n0 + n4);
    }
    __syncthreads();

    // B fragments (x), built once: bx[ct2][kc], element j = x[kc*32+lg*8+j][ct2*16+l15]
    half8 bx[4][4];
    #pragma unroll
    for (int ct2 = 0; ct2 < 4; ++ct2) {
        int n = ct2 * 16 + l15;
        #pragma unroll
        for (int kc = 0; kc < 4; ++kc) {
            half8 h;
            #pragma unroll
            for (int j = 0; j < 8; ++j) {
                int c = kc * 32 + lg * 8 + j;
                h[j] = (_Float16)(*(const float*)(xsm + xs_addr(c, n)));
            }
            bx[ct2][kc] = h;
        }
    }

    #pragma unroll 1
    for (int mat = 0; mat < 3; ++mat) {
        const float* __restrict__ W  = (mat == 0) ? wq : ((mat == 1) ? wk : wv);
        const float* __restrict__ bi = (mat == 0) ? bq : ((mat == 1) ? bk : bv);

        // A fragments (W): row = l15 -> out-chan obase+l15, k = lg*8+j
        half8 aw[4];
        #pragma unroll
        for (int kc = 0; kc < 4; ++kc) {
            const float* wp = W + (size_t)(obase + l15) * NC + kc * 32 + lg * 8;
            float4 w0 = *(const float4*)(wp);
            float4 w1 = *(const float4*)(wp + 4);
            half8 h;
            h[0] = (_Float16)w0.x; h[1] = (_Float16)w0.y; h[2] = (_Float16)w0.z; h[3] = (_Float16)w0.w;
            h[4] = (_Float16)w1.x; h[5] = (_Float16)w1.y; h[6] = (_Float16)w1.z; h[7] = (_Float16)w1.w;
            aw[kc] = h;
        }
        float bvv[4];
        #pragma unroll
        for (int r = 0; r < 4; ++r) bvv[r] = bi[obase + lg * 4 + r];

        f32x4 acc[4];
        #pragma unroll
        for (int ct2 = 0; ct2 < 4; ++ct2) acc[ct2] = (f32x4){0.f, 0.f, 0.f, 0.f};
        #pragma unroll
        for (int kc = 0; kc < 4; ++kc) {
            #pragma unroll
            for (int ct2 = 0; ct2 < 4; ++ct2)
                acc[ct2] = __builtin_amdgcn_mfma_f32_16x16x32_f16(aw[kc], bx[ct2][kc], acc[ct2], 0, 0, 0);
        }

        // D layout: row (out-chan) = lg*4+r, col (pixel) = l15 per ct2
        if (mat < 2) {
            _Float16* dst = (mat == 0) ? Qb : Kb;
            #pragma unroll
            for (int ct2 = 0; ct2 < 4; ++ct2) {
                int n = n0 + ct2 * 16 + l15;
                #pragma unroll
                for (int r = 0; r < 4; ++r)
                    dst[(size_t)(b * NN + n) * NC + obase + lg * 4 + r] = (_Float16)(acc[ct2][r] + bvv[r]);
            }
        } else {
            #pragma unroll
            for (int ct2 = 0; ct2 < 4; ++ct2) {
                int n = n0 + ct2 * 16 + l15;
                #pragma unroll
                for (int r = 0; r < 4; ++r)
                    Vt[(size_t)(b * NC + obase + lg * 4 + r) * NN + n] = (_Float16)(acc[ct2][r] + bvv[r]);
            }
        }
    }
}

// ---------------------------------------------------------------------------
// Kernel 2: fused flash attention. grid 256, block 512 = 8 waves.
// Wave (qw,kw): 16 q-rows (qw of 4), kv-half kw (32 of each 64-row tile).
// Swapped QK^T (A=K, B=Q) with permuted K-row LDS placement so each lane's
// 8 score regs ARE its PV A-fragment (in-lane softmax, no P LDS, no bpermute
// except 2 cross-lg reduces). Double-buffered K/V LDS, 1 barrier/iter.
// kv-split partials merged in LDS at the end; coalesced float4 store.
// ---------------------------------------------------------------------------
__global__ __launch_bounds__(512, 2) void attn_kernel(
    const _Float16* __restrict__ Qb, const _Float16* __restrict__ Kb,
    const _Float16* __restrict__ Vt, float* __restrict__ out)
{
    const int tid = threadIdx.x;
    const int bid = blockIdx.x;
    // XCD swizzle: bid%8 = XCD; pin each XCD to one batch (2 XCDs/batch)
    const int b  = (bid & 7) >> 1;
    const int qt = ((bid >> 3) << 1) | (bid & 1);
    const int n0 = qt << 6;

    const int lane = tid & 63;
    const int wave = __builtin_amdgcn_readfirstlane(tid >> 6);
    const int qw = wave >> 1, kw = wave & 1;
    const int l15 = lane & 15, lg = lane >> 4;

    // buf0 [0,32768): K[64][128]h (permuted rows, swizzled) + V[128][64]h (swizzled)
    // buf1 [32768,65536): same. Epilogue reuses [0,34816) as obuf, stats at 34816.
    __shared__ __align__(16) unsigned char smem[65536];

    // Q fragments (B operand): row=l15 -> q=n0+qw*16+l15, k=lg*8+j (channel)
    half8 aq[4];
    {
        const _Float16* qrow = Qb + (size_t)(b * NN + n0 + qw * 16 + l15) * NC + lg * 8;
        #pragma unroll
        for (int kc = 0; kc < 4; ++kc) aq[kc] = *(const half8*)(qrow + kc * 32);
    }

    // staging offsets: 512 threads, 2 x 16B of K + 2 x 16B of V each
    int kdst[2], ksrc[2], vdst[2], vsrc[2];
    #pragma unroll
    for (int kk = 0; kk < 2; ++kk) {
        int g = kk * 512 + tid;
        int r = g >> 4, cb = g & 15;
        // permuted LDS row: kv r -> lam = KW*32 | CT*16 | G*4 | R
        int lam = (r & 32) | (((r >> 2) & 1) << 4) | (((r >> 3) & 3) << 2) | (r & 3);
        kdst[kk] = ((lam << 8) + (cb << 4)) ^ ((lam & 7) << 4);
        ksrc[kk] = r * NC + cb * 8;
        int c = g >> 3, cb2 = g & 7;
        vdst[kk] = 16384 + (((c << 7) + (cb2 << 4)) ^ ((c & 7) << 4));
        vsrc[kk] = c * NN + cb2 * 8;
    }
    const _Float16* Kbase = Kb + (size_t)b * NN * NC;
    const _Float16* Vbase = Vt + (size_t)b * NC * NN;

    // K fragment reads: standard rows (kw*2+ct)*16 + l15 (permutation was at staging)
    int koff[2][4];
    #pragma unroll
    for (int ct = 0; ct < 2; ++ct) {
        int lrow = (kw * 2 + ct) * 16 + l15;
        #pragma unroll
        for (int kc = 0; kc < 4; ++kc)
            koff[ct][kc] = ((lrow << 8) + (kc << 6) + (lg << 4)) ^ ((lrow & 7) << 4);
    }
    int voff[8];
    #pragma unroll
    for (int ct2 = 0; ct2 < 8; ++ct2) {
        int c = ct2 * 16 + l15;
        voff[ct2] = 16384 + (((c << 7) + (kw << 6) + (lg << 4)) ^ ((c & 7) << 4));
    }

    float mrun = -3.0e38f, lsum = 0.f;
    f32x4 o[8];
    #pragma unroll
    for (int i = 0; i < 8; ++i) o[i] = (f32x4){0.f, 0.f, 0.f, 0.f};

    // prologue: tile 0 -> buf0, tile 1 -> regs
    uint4 kreg[2], vreg[2];
    #pragma unroll
    for (int kk = 0; kk < 2; ++kk) {
        kreg[kk] = *(const uint4*)(Kbase + ksrc[kk]);
        vreg[kk] = *(const uint4*)(Vbase + vsrc[kk]);
    }
    #pragma unroll
    for (int kk = 0; kk < 2; ++kk) {
        *(uint4*)(smem + kdst[kk]) = kreg[kk];
        *(uint4*)(smem + vdst[kk]) = vreg[kk];
    }
    #pragma unroll
    for (int kk = 0; kk < 2; ++kk) {
        kreg[kk] = *(const uint4*)(Kbase + (size_t)64 * NC + ksrc[kk]);
        vreg[kk] = *(const uint4*)(Vbase + 64 + vsrc[kk]);
    }
    __syncthreads();

    for (int it = 0; it < 64; ++it) {
        const int cbase = (it & 1) << 15;
        const int nbase = cbase ^ 32768;
        if (it < 63) {                       // stage tile it+1 into the other buffer
            #pragma unroll
            for (int kk = 0; kk < 2; ++kk) {
                *(uint4*)(smem + nbase + kdst[kk]) = kreg[kk];
                *(uint4*)(smem + nbase + vdst[kk]) = vreg[kk];
            }
        }
        if (it < 62) {                       // prefetch tile it+2 into regs
            size_t m0 = (size_t)(it + 2) * 64;
            #pragma unroll
            for (int kk = 0; kk < 2; ++kk) {
                kreg[kk] = *(const uint4*)(Kbase + m0 * NC + ksrc[kk]);
                vreg[kk] = *(const uint4*)(Vbase + m0 + vsrc[kk]);
            }
        }

        // ---- S = K Q^T : lane holds S[kv = kw*32 + lg*8 + ct*4 + reg][q=l15] ----
        f32x4 s[2];
        s[0] = (f32x4){0.f, 0.f, 0.f, 0.f};
        s[1] = (f32x4){0.f, 0.f, 0.f, 0.f};
        #pragma unroll
        for (int kc = 0; kc < 4; ++kc) {
            #pragma unroll
            for (int ct = 0; ct < 2; ++ct) {
                half8 kf = *(const half8*)(smem + cbase + koff[ct][kc]);
                s[ct] = __builtin_amdgcn_mfma_f32_16x16x32_f16(kf, aq[kc], s[ct], 0, 0, 0);
            }
        }

        // ---- online softmax, fully in-lane (row q = l15) ----
        float tmax = fmaxf(fmaxf(fmaxf(s[0][0], s[0][1]), fmaxf(s[0][2], s[0][3])),
                           fmaxf(fmaxf(s[1][0], s[1][1]), fmaxf(s[1][2], s[1][3])));
        tmax = fmaxf(tmax, __shfl_xor(tmax, 16, 64));
        tmax = fmaxf(tmax, __shfl_xor(tmax, 32, 64));
        float mnew = fmaxf(mrun, tmax);
        bool grow = __any(mnew > mrun);

        float p[8];
        float psum = 0.f;
        #pragma unroll
        for (int j = 0; j < 8; ++j) {
            p[j] = __expf(s[j >> 2][j & 3] - mnew);
            psum += p[j];
        }
        psum += __shfl_xor(psum, 16, 64);
        psum += __shfl_xor(psum, 32, 64);

        if (grow) {
            float sc = __expf(mrun - mnew);
            float fr0 = __shfl(sc, lg * 4 + 0, 64);
            float fr1 = __shfl(sc, lg * 4 + 1, 64);
            float fr2 = __shfl(sc, lg * 4 + 2, 64);
            float fr3 = __shfl(sc, lg * 4 + 3, 64);
            #pragma unroll
            for (int ct2 = 0; ct2 < 8; ++ct2) {
                o[ct2][0] *= fr0; o[ct2][1] *= fr1; o[ct2][2] *= fr2; o[ct2][3] *= fr3;
            }
            lsum = lsum * sc + psum;
        } else {
            lsum += psum;
        }
        mrun = mnew;

        // ---- P -> A fragment (in-lane): pa[j] = P[q=l15][kv = kw*32 + lg*8 + j] ----
        half8 pa;
        #pragma unroll
        for (int j = 0; j < 8; ++j) pa[j] = (_Float16)p[j];

        // ---- O += P V : B = V[c][kv-half kw] ----
        #pragma unroll
        for (int ct2 = 0; ct2 < 8; ++ct2) {
            half8 vf = *(const half8*)(smem + cbase + voff[ct2]);
            o[ct2] = __builtin_amdgcn_mfma_f32_16x16x32_f16(pa, vf, o[ct2], 0, 0, 0);
        }
        __syncthreads();
    }

    // ---- epilogue: merge kw=0/1 partials, normalize, coalesced store ----
    float* stat_m = (float*)(smem + 34816);
    float* stat_l = (float*)(smem + 35328);
    if (lg == 0) {
        stat_m[wave * 16 + l15] = mrun;
        stat_l[wave * 16 + l15] = lsum;
    }
    __syncthreads();
    {
        int pw = qw * 2 + (kw ^ 1);
        float mo = stat_m[pw * 16 + l15];
        float lo = stat_l[pw * 16 + l15];
        float ms  = fmaxf(mrun, mo);
        float scm = __expf(mrun - ms);
        float sco = __expf(mo - ms);
        float f   = scm / (lsum * scm + lo * sco);
        float fr0 = __shfl(f, lg * 4 + 0, 64);
        float fr1 = __shfl(f, lg * 4 + 1, 64);
        float fr2 = __shfl(f, lg * 4 + 2, 64);
        float fr3 = __shfl(f, lg * 4 + 3, 64);

        float* obuf = (float*)smem;   // [128 c][68] f32
        if (kw == 0) {
            #pragma unroll
            for (int ct2 = 0; ct2 < 8; ++ct2) {
                int base = (ct2 * 16 + l15) * 68 + qw * 16 + lg * 4;
                obuf[base + 0] = o[ct2][0] * fr0;
                obuf[base + 1] = o[ct2][1] * fr1;
                obuf[base + 2] = o[ct2][2] * fr2;
                obuf[base + 3] = o[ct2][3] * fr3;
            }
        }
        __syncthreads();
        if (kw == 1) {
            #pragma unroll
            for (int ct2 = 0; ct2 < 8; ++ct2) {
                int base = (ct2 * 16 + l15) * 68 + qw * 16 + lg * 4;
                obuf[base + 0] += o[ct2][0] * fr0;
                obuf[base + 1] += o[ct2][1] * fr1;
                obuf[base + 2] += o[ct2][2] * fr2;
                obuf[base + 3] += o[ct2][3] * fr3;
            }
        }
        __syncthreads();

        const int c  = tid >> 2;
        const int nq = (tid & 3) << 2;
        float* orow = out + (size_t)(b * NC + c) * NN + n0;
        #pragma unroll
        for (int i = 0; i < 4; ++i) {
            float4 v = *(float4*)(&obuf[c * 68 + nq + i * 16]);
            *(float4*)(orow + nq + i * 16) = v;
        }
    }
}

extern "C" void kernel_launch(void* const* d_in, const int* in_sizes, int n_in,
                              void* d_out, int out_size, void* d_ws, size_t ws_size,
                              hipStream_t stream)
{
    const float* x  = (const float*)d_in[0];
    const float* wq = (const float*)d_in[1];
    const float* bq = (const float*)d_in[2];
    const float* wk = (const float*)d_in[3];
    const float* bk = (const float*)d_in[4];
    const float* wv = (const float*)d_in[5];
    const float* bv = (const float*)d_in[6];

    _Float16* Qb = (_Float16*)d_ws;                    // [B,N,C] fp16
    _Float16* Kb = Qb + (size_t)NB * NN * NC;          // [B,N,C] fp16
    _Float16* Vb = Kb + (size_t)NB * NN * NC;          // [B,C,N] fp16

    qkv_proj_kernel<<<dim3(256), dim3(512), 0, stream>>>(x, wq, bq, wk, bk, wv, bv, Qb, Kb, Vb);
    attn_kernel<<<dim3(256), dim3(512), 0, stream>>>(Qb, Kb, Vb, (float*)d_out);
}

// Round 3
// 117.048 us; speedup vs baseline: 3.1130x; 1.3013x over previous
//
#include <hip/hip_runtime.h>

typedef _Float16 half8 __attribute__((ext_vector_type(8)));
typedef float f32x4 __attribute__((ext_vector_type(4)));
typedef unsigned int u32;
typedef unsigned short u16;

#define NB 4
#define NC 128
#define NN 4096

__device__ __forceinline__ void gload16(const void* g, void* l) {
    __builtin_amdgcn_global_load_lds(
        (const __attribute__((address_space(1))) u32*)g,
        (__attribute__((address_space(3))) u32*)l, 16, 0, 0);
}
__device__ __forceinline__ float h2f_u(u32 u) {   // low 16 bits as fp16 -> f32
    u16 us = (u16)u;
    _Float16 h;
    __builtin_memcpy(&h, &us, 2);
    return (float)h;
}
__device__ __forceinline__ u16 f2h_u(float f) {
    _Float16 h = (_Float16)f;
    u16 us;
    __builtin_memcpy(&us, &h, 2);
    return us;
}

// swizzled byte address for x-tile LDS [c][n] f32 (proj kernel)
__device__ __forceinline__ int xs_addr(int c, int n) {
    return ((c << 8) + (n << 2)) ^ (((c >> 3) & 1) << 6);
}

// ---------------------------------------------------------------------------
// Kernel 1: QKV projection via fp16 MFMA (unchanged from round 2, ~5 us).
// ---------------------------------------------------------------------------
__global__ __launch_bounds__(512, 2) void qkv_proj_kernel(
    const float* __restrict__ x,
    const float* __restrict__ wq, const float* __restrict__ bq,
    const float* __restrict__ wk, const float* __restrict__ bk,
    const float* __restrict__ wv, const float* __restrict__ bv,
    _Float16* __restrict__ Qb, _Float16* __restrict__ Kb, _Float16* __restrict__ Vt)
{
    const int tid  = threadIdx.x;
    const int b    = blockIdx.x >> 6;
    const int n0   = (blockIdx.x & 63) << 6;
    const int lane = tid & 63;
    const int wave = __builtin_amdgcn_readfirstlane(tid >> 6);
    const int l15  = lane & 15, lg = lane >> 4;
    const int obase = wave * 16;

    __shared__ __align__(16) unsigned char xsm[32768];

    #pragma unroll
    for (int kk = 0; kk < 4; ++kk) {
        int g = kk * 512 + tid;
        int c = g >> 4, n4 = (g & 15) << 2;
        *(float4*)(xsm + xs_addr(c, n4)) = *(const float4*)(x + (size_t)(b * NC + c) * NN + n0 + n4);
    }
    __syncthreads();

    half8 bx[4][4];
    #pragma unroll
    for (int ct2 = 0; ct2 < 4; ++ct2) {
        int n = ct2 * 16 + l15;
        #pragma unroll
        for (int kc = 0; kc < 4; ++kc) {
            half8 h;
            #pragma unroll
            for (int j = 0; j < 8; ++j) {
                int c = kc * 32 + lg * 8 + j;
                h[j] = (_Float16)(*(const float*)(xsm + xs_addr(c, n)));
            }
            bx[ct2][kc] = h;
        }
    }

    #pragma unroll 1
    for (int mat = 0; mat < 3; ++mat) {
        const float* __restrict__ W  = (mat == 0) ? wq : ((mat == 1) ? wk : wv);
        const float* __restrict__ bi = (mat == 0) ? bq : ((mat == 1) ? bk : bv);

        half8 aw[4];
        #pragma unroll
        for (int kc = 0; kc < 4; ++kc) {
            const float* wp = W + (size_t)(obase + l15) * NC + kc * 32 + lg * 8;
            float4 w0 = *(const float4*)(wp);
            float4 w1 = *(const float4*)(wp + 4);
            half8 h;
            h[0] = (_Float16)w0.x; h[1] = (_Float16)w0.y; h[2] = (_Float16)w0.z; h[3] = (_Float16)w0.w;
            h[4] = (_Float16)w1.x; h[5] = (_Float16)w1.y; h[6] = (_Float16)w1.z; h[7] = (_Float16)w1.w;
            aw[kc] = h;
        }
        float bvv[4];
        #pragma unroll
        for (int r = 0; r < 4; ++r) bvv[r] = bi[obase + lg * 4 + r];

        f32x4 acc[4];
        #pragma unroll
        for (int ct2 = 0; ct2 < 4; ++ct2) acc[ct2] = (f32x4){0.f, 0.f, 0.f, 0.f};
        #pragma unroll
        for (int kc = 0; kc < 4; ++kc) {
            #pragma unroll
            for (int ct2 = 0; ct2 < 4; ++ct2)
                acc[ct2] = __builtin_amdgcn_mfma_f32_16x16x32_f16(aw[kc], bx[ct2][kc], acc[ct2], 0, 0, 0);
        }

        if (mat < 2) {
            _Float16* dst = (mat == 0) ? Qb : Kb;
            #pragma unroll
            for (int ct2 = 0; ct2 < 4; ++ct2) {
                int n = n0 + ct2 * 16 + l15;
                #pragma unroll
                for (int r = 0; r < 4; ++r)
                    dst[(size_t)(b * NN + n) * NC + obase + lg * 4 + r] = (_Float16)(acc[ct2][r] + bvv[r]);
            }
        } else {
            #pragma unroll
            for (int ct2 = 0; ct2 < 4; ++ct2) {
                int n = n0 + ct2 * 16 + l15;
                #pragma unroll
                for (int r = 0; r < 4; ++r)
                    Vt[(size_t)(b * NC + obase + lg * 4 + r) * NN + n] = (_Float16)(acc[ct2][r] + bvv[r]);
            }
        }
    }
}

// ---------------------------------------------------------------------------
// Kernel 2: flash attention with kv-split S (runtime 1/2/4).
// grid = 256*S blocks, 256 thr = 4 waves; each wave: 16 q rows x full 64-kv
// tile per iter. Single 32KB LDS buffer staged via global_load_lds with
// pre-permuted per-lane source (linear LDS dest). 4 blocks/CU.
// Partials: fp16 bit-interleaved into d_out's u32 slots (sp0=lo, sp1=hi);
// sp2/3 in ws. Stats m,l in ws.
// ---------------------------------------------------------------------------
__global__ __launch_bounds__(256, 4) void attn_kernel(
    const _Float16* __restrict__ Qb, const _Float16* __restrict__ Kb,
    const _Float16* __restrict__ Vt, float* __restrict__ out,
    u32* __restrict__ p01, u32* __restrict__ p23,
    float* __restrict__ statM, float* __restrict__ statL, int S)
{
    const int tid = threadIdx.x;
    const int g = blockIdx.x;
    int b, sp, qt, lg2S;
    if (S == 4)      { int j = g >> 3; int pair = ((g & 7) << 1) | (j >> 6); b = pair >> 2; sp = pair & 3; qt = j & 63; lg2S = 2; }
    else if (S == 2) { b = (g & 7) >> 1; sp = g & 1; qt = g >> 3; lg2S = 1; }
    else             { b = (g & 7) >> 1; sp = 0; qt = ((g >> 3) << 1) | (g & 1); lg2S = 0; }

    const int n0    = qt << 6;
    const int kvlen = NN >> lg2S;
    const int kv0   = sp * kvlen;
    const int iters = kvlen >> 6;

    const int lane = tid & 63;
    const int wave = __builtin_amdgcn_readfirstlane(tid >> 6);
    const int l15 = lane & 15, lg = lane >> 4;

    // [0,16K): K tile (permuted rows, swizzled); [16K,32K): V tile (swizzled)
    // epilogue: obuf f32 [128 c][66]
    __shared__ __align__(16) unsigned char smem[33792];

    // ---- global_load_lds per-lane source offsets (linear LDS dest) ----
    int kgo[4], vgo[4], kl[4], vl[4];
    #pragma unroll
    for (int c = 0; c < 4; ++c) {
        int qc = wave * 4 + c;
        int d  = qc * 1024 + lane * 16;
        // K: invert row-permutation + XOR swizzle
        int lam = d >> 8;
        int w8  = (d & 255) ^ ((lam & 7) << 4);
        int r = (lam & 32) | (((lam >> 3) & 1) << 4) | (((lam >> 2) & 1) << 3)
              | (((lam >> 4) & 1) << 2) | (lam & 3);
        kgo[c] = r * NC + (w8 >> 1);
        kl[c]  = qc * 1024;
        // V: [128 c][64 kv] halves, XOR swizzle only
        int cr = d >> 7;
        int wv2 = (d & 127) ^ ((cr & 7) << 4);
        vgo[c] = cr * NN + (wv2 >> 1);
        vl[c]  = 16384 + qc * 1024;
    }

    // ---- fragment read bases (decomposed swizzle; m = (l15&7)<<4) ----
    const int m = (l15 & 7) << 4;
    int kaddr[4], vaddr[2];
    {
        int B0 = ((l15 << 8) + ((lg << 4) ^ (m & 48)));
        int V0 = 16384 + ((l15 << 7) + ((lg << 4) ^ (m & 48)));
        #pragma unroll
        for (int kc = 0; kc < 4; ++kc) kaddr[kc] = B0 + ((kc << 6) ^ (m & 64));
        #pragma unroll
        for (int h = 0; h < 2; ++h)   vaddr[h] = V0 + ((h << 6) ^ (m & 64));
    }

    const _Float16* Kt0 = Kb + (size_t)b * NN * NC + (size_t)kv0 * NC;
    const _Float16* Vt0 = Vt + (size_t)b * NC * NN + kv0;

    // prologue: stage tile 0, load Q frags
    #pragma unroll
    for (int c = 0; c < 4; ++c) {
        gload16(Kt0 + kgo[c], smem + kl[c]);
        gload16(Vt0 + vgo[c], smem + vl[c]);
    }
    half8 aq[4];
    {
        const _Float16* qrow = Qb + (size_t)(b * NN + n0 + wave * 16 + l15) * NC + lg * 8;
        #pragma unroll
        for (int kc = 0; kc < 4; ++kc) aq[kc] = *(const half8*)(qrow + kc * 32);
    }
    asm volatile("s_waitcnt vmcnt(0)" ::: "memory");
    __syncthreads();

    float mrun = -3.0e38f, lsum = 0.f;
    f32x4 o[8];
    #pragma unroll
    for (int i = 0; i < 8; ++i) o[i] = (f32x4){0.f, 0.f, 0.f, 0.f};

    for (int it = 0; it < iters; ++it) {
        // ---- S = K Q^T : lane holds S[kv-slot][q=l15], slot = row-perm id ----
        f32x4 s[4];
        #pragma unroll
        for (int ct = 0; ct < 4; ++ct) s[ct] = (f32x4){0.f, 0.f, 0.f, 0.f};
        #pragma unroll
        for (int kc = 0; kc < 4; ++kc) {
            #pragma unroll
            for (int ct = 0; ct < 4; ++ct) {
                half8 kf = *(const half8*)(smem + kaddr[kc] + ct * 4096);
                s[ct] = __builtin_amdgcn_mfma_f32_16x16x32_f16(kf, aq[kc], s[ct], 0, 0, 0);
            }
        }

        // ---- online softmax (full 64-kv row, in-lane + 2 shfl) ----
        float tmax = s[0][0];
        #pragma unroll
        for (int ct = 0; ct < 4; ++ct)
            #pragma unroll
            for (int rg = 0; rg < 4; ++rg) tmax = fmaxf(tmax, s[ct][rg]);
        tmax = fmaxf(tmax, __shfl_xor(tmax, 16, 64));
        tmax = fmaxf(tmax, __shfl_xor(tmax, 32, 64));
        float mnew = fmaxf(mrun, tmax);
        bool grow = __any(mnew > mrun);

        float p[16];
        float psum = 0.f;
        #pragma unroll
        for (int ct = 0; ct < 4; ++ct)
            #pragma unroll
            for (int rg = 0; rg < 4; ++rg) {
                float pv = __expf(s[ct][rg] - mnew);
                p[ct * 4 + rg] = pv;
                psum += pv;
            }
        psum += __shfl_xor(psum, 16, 64);
        psum += __shfl_xor(psum, 32, 64);

        if (grow) {
            float sc = __expf(mrun - mnew);
            float fr0 = __shfl(sc, lg * 4 + 0, 64);
            float fr1 = __shfl(sc, lg * 4 + 1, 64);
            float fr2 = __shfl(sc, lg * 4 + 2, 64);
            float fr3 = __shfl(sc, lg * 4 + 3, 64);
            #pragma unroll
            for (int ct2 = 0; ct2 < 8; ++ct2) {
                o[ct2][0] *= fr0; o[ct2][1] *= fr1; o[ct2][2] *= fr2; o[ct2][3] *= fr3;
            }
            lsum = lsum * sc + psum;
        } else {
            lsum += psum;
        }
        mrun = mnew;

        // ---- P -> A frags (slot identity: pa0 = kv 0..31, pa1 = 32..63) ----
        half8 pa0, pa1;
        #pragma unroll
        for (int j = 0; j < 8; ++j) { pa0[j] = (_Float16)p[j]; pa1[j] = (_Float16)p[8 + j]; }

        // ---- O += P V ----
        #pragma unroll
        for (int ct2 = 0; ct2 < 8; ++ct2) {
            half8 v0 = *(const half8*)(smem + vaddr[0] + ct2 * 2048);
            o[ct2] = __builtin_amdgcn_mfma_f32_16x16x32_f16(pa0, v0, o[ct2], 0, 0, 0);
            half8 v1 = *(const half8*)(smem + vaddr[1] + ct2 * 2048);
            o[ct2] = __builtin_amdgcn_mfma_f32_16x16x32_f16(pa1, v1, o[ct2], 0, 0, 0);
        }
        __syncthreads();                       // everyone done reading tile

        if (it + 1 < iters) {                  // stage next tile
            const _Float16* Kt = Kt0 + (size_t)(it + 1) * 64 * NC;
            const _Float16* Vn = Vt0 + (it + 1) * 64;
            #pragma unroll
            for (int c = 0; c < 4; ++c) {
                gload16(Kt + kgo[c], smem + kl[c]);
                gload16(Vn + vgo[c], smem + vl[c]);
            }
            asm volatile("s_waitcnt vmcnt(0)" ::: "memory");
            __syncthreads();
        }
    }

    // ---- epilogue ----
    if (S > 1 && lg == 0) {
        int n = n0 + wave * 16 + l15;
        statM[(sp * NB + b) * NN + n] = mrun;
        statL[(sp * NB + b) * NN + n] = lsum;
    }
    if (S == 1) {                               // normalize in-place
        float f1 = 1.0f / lsum;
        float q0 = __shfl(f1, lg * 4 + 0, 64);
        float q1 = __shfl(f1, lg * 4 + 1, 64);
        float q2 = __shfl(f1, lg * 4 + 2, 64);
        float q3 = __shfl(f1, lg * 4 + 3, 64);
        #pragma unroll
        for (int ct2 = 0; ct2 < 8; ++ct2) {
            o[ct2][0] *= q0; o[ct2][1] *= q1; o[ct2][2] *= q2; o[ct2][3] *= q3;
        }
    }

    float* obuf = (float*)smem;                 // [128 c][66]
    #pragma unroll
    for (int ct2 = 0; ct2 < 8; ++ct2) {
        int c = ct2 * 16 + l15;
        #pragma unroll
        for (int rg = 0; rg < 4; ++rg)
            obuf[c * 66 + wave * 16 + lg * 4 + rg] = o[ct2][rg];
    }
    __syncthreads();

    {
        const int c  = tid >> 1;
        const int nh = (tid & 1) << 5;
        if (S == 1) {
            float* orow = out + (size_t)(b * NC + c) * NN + n0 + nh;
            #pragma unroll
            for (int i = 0; i < 8; ++i)
                *(float4*)(orow + i * 4) = *(float4*)(&obuf[c * 66 + nh + i * 4]);
        } else {
            u16* pp = (u16*)(sp < 2 ? p01 : p23);
            const int hs = sp & 1;
            size_t eb = (size_t)(b * NC + c) * NN + n0 + nh;
            #pragma unroll
            for (int i = 0; i < 32; ++i)
                pp[((eb + i) << 1) | hs] = f2h_u(obuf[c * 66 + nh + i]);
        }
    }
}

// ---------------------------------------------------------------------------
// Kernel 3: merge S partials. Each thread reads exactly the d_out bytes it
// overwrites (race-free aliasing). grid = B*N/16, block 256.
// ---------------------------------------------------------------------------
__global__ __launch_bounds__(256) void merge_kernel(
    const u32* __restrict__ p01, const u32* __restrict__ p23,
    const float* __restrict__ statM, const float* __restrict__ statL,
    float* __restrict__ out, int S)
{
    const int blk = blockIdx.x;
    const int b  = blk >> 8;
    const int n0 = (blk & 255) << 4;
    const int t  = threadIdx.x;
    const int c  = t >> 1;
    const int ni = (t & 1) << 3;
    const size_t base = ((size_t)(b * NC + c) << 12) + n0 + ni;

    float w0[8], w1[8], w2[8], w3[8];
    #pragma unroll
    for (int j = 0; j < 8; ++j) {
        int n = n0 + ni + j;
        float m0 = statM[(0 * NB + b) * NN + n], l0 = statL[(0 * NB + b) * NN + n];
        float m1 = statM[(1 * NB + b) * NN + n], l1 = statL[(1 * NB + b) * NN + n];
        if (S == 4) {
            float m2 = statM[(2 * NB + b) * NN + n], l2 = statL[(2 * NB + b) * NN + n];
            float m3 = statM[(3 * NB + b) * NN + n], l3 = statL[(3 * NB + b) * NN + n];
            float M = fmaxf(fmaxf(m0, m1), fmaxf(m2, m3));
            float e0 = __expf(m0 - M), e1 = __expf(m1 - M);
            float e2 = __expf(m2 - M), e3 = __expf(m3 - M);
            float inv = 1.f / (e0 * l0 + e1 * l1 + e2 * l2 + e3 * l3);
            w0[j] = e0 * inv; w1[j] = e1 * inv; w2[j] = e2 * inv; w3[j] = e3 * inv;
        } else {
            float M = fmaxf(m0, m1);
            float e0 = __expf(m0 - M), e1 = __expf(m1 - M);
            float inv = 1.f / (e0 * l0 + e1 * l1);
            w0[j] = e0 * inv; w1[j] = e1 * inv; w2[j] = 0.f; w3[j] = 0.f;
        }
    }

    uint4 a0 = *(const uint4*)(p01 + base);
    uint4 a1 = *(const uint4*)(p01 + base + 4);
    u32 aa[8] = {a0.x, a0.y, a0.z, a0.w, a1.x, a1.y, a1.z, a1.w};
    float acc[8];
    #pragma unroll
    for (int j = 0; j < 8; ++j)
        acc[j] = w0[j] * h2f_u(aa[j]) + w1[j] * h2f_u(aa[j] >> 16);
    if (S == 4) {
        uint4 b0 = *(const uint4*)(p23 + base);
        uint4 b1 = *(const uint4*)(p23 + base + 4);
        u32 bb[8] = {b0.x, b0.y, b0.z, b0.w, b1.x, b1.y, b1.z, b1.w};
        #pragma unroll
        for (int j = 0; j < 8; ++j)
            acc[j] += w2[j] * h2f_u(bb[j]) + w3[j] * h2f_u(bb[j] >> 16);
    }
    float4 r0 = {acc[0], acc[1], acc[2], acc[3]};
    float4 r1 = {acc[4], acc[5], acc[6], acc[7]};
    *(float4*)(out + base)     = r0;
    *(float4*)(out + base + 4) = r1;
}

extern "C" void kernel_launch(void* const* d_in, const int* in_sizes, int n_in,
                              void* d_out, int out_size, void* d_ws, size_t ws_size,
                              hipStream_t stream)
{
    const float* x  = (const float*)d_in[0];
    const float* wq = (const float*)d_in[1];
    const float* bq = (const float*)d_in[2];
    const float* wk = (const float*)d_in[3];
    const float* bk = (const float*)d_in[4];
    const float* wv = (const float*)d_in[5];
    const float* bv = (const float*)d_in[6];

    const size_t TE = (size_t)NB * NN * NC;        // elements per fp16 tensor
    _Float16* Qb = (_Float16*)d_ws;
    _Float16* Kb = Qb + TE;
    _Float16* Vb = Kb + TE;
    const size_t statOff = 3 * TE * 2;             // 12 MB
    float* statM = (float*)((char*)d_ws + statOff);
    float* statL = statM + 4 * (size_t)NB * NN;    // 256 KB reserved for M
    const size_t p23Off = statOff + 2 * 4 * (size_t)NB * NN * 4;   // 12 MB + 512 KB
    u32* p23 = (u32*)((char*)d_ws + p23Off);
    u32* p01 = (u32*)d_out;

    int S;
    if (ws_size >= p23Off + (size_t)NB * NC * NN * 4) S = 4;   // + 8 MB partials
    else if (ws_size >= p23Off)                        S = 2;
    else                                               S = 1;

    qkv_proj_kernel<<<dim3(256), dim3(512), 0, stream>>>(x, wq, bq, wk, bk, wv, bv, Qb, Kb, Vb);
    attn_kernel<<<dim3(256 * S), dim3(256), 0, stream>>>(Qb, Kb, Vb, (float*)d_out,
                                                         p01, p23, statM, statL, S);
    if (S > 1)
        merge_kernel<<<dim3(NB * (NN / 16)), dim3(256), 0, stream>>>(p01, p23, statM, statL,
                                                                     (float*)d_out, S);
}

// Round 5
// 82.116 us; speedup vs baseline: 4.4373x; 1.4254x over previous
//
#include <hip/hip_runtime.h>

typedef _Float16 half8 __attribute__((ext_vector_type(8)));
typedef __fp16 fp16x2 __attribute__((ext_vector_type(2)));
typedef float f32x4 __attribute__((ext_vector_type(4)));
typedef float f32x16 __attribute__((ext_vector_type(16)));
typedef unsigned int u32;
typedef unsigned short u16;

#define NB 4
#define NC 128
#define NN 4096

__device__ __forceinline__ void gload16(const void* g, void* l) {
    __builtin_amdgcn_global_load_lds(
        (const __attribute__((address_space(1))) u32*)g,
        (__attribute__((address_space(3))) u32*)l, 16, 0, 0);
}
__device__ __forceinline__ float h2f_u(u32 u) {
    u16 us = (u16)u;
    _Float16 h;
    __builtin_memcpy(&h, &us, 2);
    return (float)h;
}
__device__ __forceinline__ u16 f2h_u(float f) {
    _Float16 h = (_Float16)f;
    u16 us;
    __builtin_memcpy(&us, &h, 2);
    return us;
}
__device__ __forceinline__ int xs_addr(int c, int n) {
    return ((c << 8) + (n << 2)) ^ (((c >> 3) & 1) << 6);
}

// ---------------------------------------------------------------------------
// Kernel 1: QKV projection via fp16 MFMA (unchanged; works).
// ---------------------------------------------------------------------------
__global__ __launch_bounds__(512, 2) void qkv_proj_kernel(
    const float* __restrict__ x,
    const float* __restrict__ wq, const float* __restrict__ bq,
    const float* __restrict__ wk, const float* __restrict__ bk,
    const float* __restrict__ wv, const float* __restrict__ bv,
    _Float16* __restrict__ Qb, _Float16* __restrict__ Kb, _Float16* __restrict__ Vt)
{
    const int tid  = threadIdx.x;
    const int b    = blockIdx.x >> 6;
    const int n0   = (blockIdx.x & 63) << 6;
    const int lane = tid & 63;
    const int wave = __builtin_amdgcn_readfirstlane(tid >> 6);
    const int l15  = lane & 15, lg = lane >> 4;
    const int obase = wave * 16;

    __shared__ __align__(16) unsigned char xsm[32768];

    #pragma unroll
    for (int kk = 0; kk < 4; ++kk) {
        int g = kk * 512 + tid;
        int c = g >> 4, n4 = (g & 15) << 2;
        *(float4*)(xsm + xs_addr(c, n4)) = *(const float4*)(x + (size_t)(b * NC + c) * NN + n0 + n4);
    }
    __syncthreads();

    half8 bx[4][4];
    #pragma unroll
    for (int ct2 = 0; ct2 < 4; ++ct2) {
        int n = ct2 * 16 + l15;
        #pragma unroll
        for (int kc = 0; kc < 4; ++kc) {
            half8 h;
            #pragma unroll
            for (int j = 0; j < 8; ++j) {
                int c = kc * 32 + lg * 8 + j;
                h[j] = (_Float16)(*(const float*)(xsm + xs_addr(c, n)));
            }
            bx[ct2][kc] = h;
        }
    }

    #pragma unroll 1
    for (int mat = 0; mat < 3; ++mat) {
        const float* __restrict__ W  = (mat == 0) ? wq : ((mat == 1) ? wk : wv);
        const float* __restrict__ bi = (mat == 0) ? bq : ((mat == 1) ? bk : bv);

        half8 aw[4];
        #pragma unroll
        for (int kc = 0; kc < 4; ++kc) {
            const float* wp = W + (size_t)(obase + l15) * NC + kc * 32 + lg * 8;
            float4 w0 = *(const float4*)(wp);
            float4 w1 = *(const float4*)(wp + 4);
            half8 h;
            h[0] = (_Float16)w0.x; h[1] = (_Float16)w0.y; h[2] = (_Float16)w0.z; h[3] = (_Float16)w0.w;
            h[4] = (_Float16)w1.x; h[5] = (_Float16)w1.y; h[6] = (_Float16)w1.z; h[7] = (_Float16)w1.w;
            aw[kc] = h;
        }
        float bvv[4];
        #pragma unroll
        for (int r = 0; r < 4; ++r) bvv[r] = bi[obase + lg * 4 + r];

        f32x4 acc[4];
        #pragma unroll
        for (int ct2 = 0; ct2 < 4; ++ct2) acc[ct2] = (f32x4){0.f, 0.f, 0.f, 0.f};
        #pragma unroll
        for (int kc = 0; kc < 4; ++kc) {
            #pragma unroll
            for (int ct2 = 0; ct2 < 4; ++ct2)
                acc[ct2] = __builtin_amdgcn_mfma_f32_16x16x32_f16(aw[kc], bx[ct2][kc], acc[ct2], 0, 0, 0);
        }

        if (mat < 2) {
            _Float16* dst = (mat == 0) ? Qb : Kb;
            #pragma unroll
            for (int ct2 = 0; ct2 < 4; ++ct2) {
                int n = n0 + ct2 * 16 + l15;
                #pragma unroll
                for (int r = 0; r < 4; ++r)
                    dst[(size_t)(b * NN + n) * NC + obase + lg * 4 + r] = (_Float16)(acc[ct2][r] + bvv[r]);
            }
        } else {
            #pragma unroll
            for (int ct2 = 0; ct2 < 4; ++ct2) {
                int n = n0 + ct2 * 16 + l15;
                #pragma unroll
                for (int r = 0; r < 4; ++r)
                    Vt[(size_t)(b * NC + obase + lg * 4 + r) * NN + n] = (_Float16)(acc[ct2][r] + bvv[r]);
            }
        }
    }
}

// ---------------------------------------------------------------------------
// Kernel 2: flash attention, 32x32x16 MFMA, 32 q-rows/wave, kv-split S.
// K staged at LDS row swap23(kv) so S's D-row set IS the PV A-frag kv-set:
// softmax + P->fp16 pack fully in-lane (1 shfl_xor(32) per reduce).
// PV operand-swapped: O[c][q=l31] -> rescale/normalize in-lane.
// Single 32KB LDS tile, global_load_lds staging, 3 blocks/CU.
// ---------------------------------------------------------------------------
__global__ __launch_bounds__(256, 3) void attn_kernel(
    const _Float16* __restrict__ Qb, const _Float16* __restrict__ Kb,
    const _Float16* __restrict__ Vt, float* __restrict__ out,
    u32* __restrict__ pp1, u32* __restrict__ pp2, u32* __restrict__ pp3,
    float* __restrict__ statM, float* __restrict__ statL, int lg2S)
{
    const int S = 1 << lg2S;
    const int tid = threadIdx.x;
    // XCD swizzle: contiguous lin-chunks per XCD; nblocks % 8 == 0 always.
    const int cpx = gridDim.x >> 3;
    const int lin = (blockIdx.x & 7) * cpx + (blockIdx.x >> 3);
    const int qt   = lin & 31;
    const int rest = lin >> 5;             // = b * S + sp
    const int sp = rest & (S - 1);
    const int b  = rest >> lg2S;

    const int n0    = qt << 7;             // 128 q per block
    const int kvlen = NN >> lg2S;
    const int kv0   = sp * kvlen;
    const int iters = kvlen >> 6;

    const int lane = tid & 63;
    const int wave = __builtin_amdgcn_readfirstlane(tid >> 6);
    const int l31 = lane & 31, hi = lane >> 5;
    const int s7 = l31 & 7;

    // [0,16384): K tile 64 rows x 256B (row-permuted swap23, slot-swizzled)
    // [16384,32768): V tile 128 c-rows x 128B (slot-swizzled)
    __shared__ __align__(16) unsigned char smem[32768];

    // ---- staging source offsets (linear LDS dest; inverse of layout map) ----
    int kgo[4], vgo[4];
    #pragma unroll
    for (int j = 0; j < 4; ++j) {
        int i = (wave * 4 + j) * 64 + lane;          // chunk 0..1023 (16B units)
        int lam = i >> 4, slot = i & 15;
        int cc = (slot & 8) | ((slot & 7) ^ (lam & 7));
        int kv = (lam & 51) | ((lam & 4) << 1) | ((lam & 8) >> 1);  // swap bits 2,3
        kgo[j] = kv * NC + cc * 8;
        int c = i >> 3, s2 = i & 7;
        vgo[j] = c * NN + ((s2 ^ (c & 7)) << 3);
    }
    const _Float16* Kt0 = Kb + ((size_t)b * NN + kv0) * NC;
    const _Float16* Vt0 = Vt + (size_t)b * NC * NN + kv0;

    // ---- fragment read offsets ----
    int koff[8];
    #pragma unroll
    for (int kc = 0; kc < 8; ++kc) {
        int cc = kc * 2 + hi;
        koff[kc] = l31 * 256 + (((cc & 8) | ((cc & 7) ^ s7)) << 4);
    }
    int voff[4];
    #pragma unroll
    for (int ks = 0; ks < 4; ++ks) {
        int cc2 = ks * 2 + hi;
        voff[ks] = 16384 + l31 * 128 + ((cc2 ^ s7) << 4);
    }

    // ---- prologue: stage tile 0 + load Q fragments ----
    #pragma unroll
    for (int j = 0; j < 4; ++j) {
        gload16(Kt0 + kgo[j], smem + (wave * 4 + j) * 1024);
        gload16(Vt0 + vgo[j], smem + 16384 + (wave * 4 + j) * 1024);
    }
    half8 aq[8];
    {
        const _Float16* qp = Qb + (size_t)(b * NN + n0 + wave * 32 + l31) * NC + hi * 8;
        #pragma unroll
        for (int kc = 0; kc < 8; ++kc) aq[kc] = *(const half8*)(qp + kc * 16);
    }
    asm volatile("s_waitcnt vmcnt(0)" ::: "memory");
    __syncthreads();

    float mrun = -3.0e38f, lsum = 0.f;
    f32x16 o[4];
    #pragma unroll
    for (int ct = 0; ct < 4; ++ct)
        #pragma unroll
        for (int r = 0; r < 16; ++r) o[ct][r] = 0.f;

    for (int it = 0; it < iters; ++it) {
        // ---- S = K Q^T : D[lds-row][q=l31] ----
        f32x16 s0, s1;
        #pragma unroll
        for (int r = 0; r < 16; ++r) { s0[r] = 0.f; s1[r] = 0.f; }
        #pragma unroll
        for (int kc = 0; kc < 8; ++kc) {
            half8 k0 = *(const half8*)(smem + koff[kc]);
            half8 k1 = *(const half8*)(smem + koff[kc] + 8192);
            s0 = __builtin_amdgcn_mfma_f32_32x32x16_f16(k0, aq[kc], s0, 0, 0, 0);
            s1 = __builtin_amdgcn_mfma_f32_32x32x16_f16(k1, aq[kc], s1, 0, 0, 0);
        }

        // ---- online softmax, in-lane for q = l31 ----
        float tmax = fmaxf(s0[0], s1[0]);
        #pragma unroll
        for (int r = 1; r < 16; ++r) tmax = fmaxf(tmax, fmaxf(s0[r], s1[r]));
        tmax = fmaxf(tmax, __shfl_xor(tmax, 32, 64));
        float mnew = fmaxf(mrun, tmax);

        float psum = 0.f;
        #pragma unroll
        for (int r = 0; r < 16; ++r) {
            s0[r] = __expf(s0[r] - mnew);
            s1[r] = __expf(s1[r] - mnew);
            psum += s0[r] + s1[r];
        }
        psum += __shfl_xor(psum, 32, 64);

        if (__any(mnew > mrun)) {
            float sc = __expf(mrun - mnew);
            #pragma unroll
            for (int ct = 0; ct < 4; ++ct)
                #pragma unroll
                for (int r = 0; r < 16; ++r) o[ct][r] *= sc;
            lsum = lsum * sc + psum;
        } else {
            lsum += psum;
        }
        mrun = mnew;

        // ---- P -> A-frags, fully in-lane (row-permuted K makes this identity) ----
        union H8 { fp16x2 h2[4]; half8 h8; };
        half8 pa[4];
        {
            H8 u0, u1, u2, u3;
            #pragma unroll
            for (int t = 0; t < 4; ++t) {
                u0.h2[t] = __builtin_amdgcn_cvt_pkrtz(s0[2 * t],     s0[2 * t + 1]);
                u1.h2[t] = __builtin_amdgcn_cvt_pkrtz(s0[8 + 2 * t], s0[9 + 2 * t]);
                u2.h2[t] = __builtin_amdgcn_cvt_pkrtz(s1[2 * t],     s1[2 * t + 1]);
                u3.h2[t] = __builtin_amdgcn_cvt_pkrtz(s1[8 + 2 * t], s1[9 + 2 * t]);
            }
            pa[0] = u0.h8; pa[1] = u1.h8; pa[2] = u2.h8; pa[3] = u3.h8;
        }

        // ---- O += V^T P : D[c][q=l31] ----
        #pragma unroll
        for (int ks = 0; ks < 4; ++ks) {
            #pragma unroll
            for (int ct = 0; ct < 4; ++ct) {
                half8 vf = *(const half8*)(smem + voff[ks] + ct * 4096);
                o[ct] = __builtin_amdgcn_mfma_f32_32x32x16_f16(vf, pa[ks], o[ct], 0, 0, 0);
            }
        }

        if (it + 1 < iters) {
            __syncthreads();                  // all reads of this tile done
            const _Float16* Kp = Kt0 + (size_t)(it + 1) * 64 * NC;
            const _Float16* Vp = Vt0 + (it + 1) * 64;
            #pragma unroll
            for (int j = 0; j < 4; ++j) {
                gload16(Kp + kgo[j], smem + (wave * 4 + j) * 1024);
                gload16(Vp + vgo[j], smem + 16384 + (wave * 4 + j) * 1024);
            }
            asm volatile("s_waitcnt vmcnt(0)" ::: "memory");
            __syncthreads();                  // tile visible
        }
    }

    // ---- epilogue (all q-column-local) ----
    const int nq = n0 + wave * 32 + l31;
    const int rbase = 4 * hi;
    if (lg2S == 0) {
        float inv = 1.0f / lsum;
        #pragma unroll
        for (int ct = 0; ct < 4; ++ct)
            #pragma unroll
            for (int rg = 0; rg < 16; ++rg) {
                int c = ct * 32 + (rg & 3) + ((rg >> 2) << 3) + rbase;
                out[(size_t)(b * NC + c) * NN + nq] = o[ct][rg] * inv;
            }
    } else {
        if (hi == 0) {
            statM[(sp * NB + b) * NN + nq] = mrun;
            statL[(sp * NB + b) * NN + nq] = lsum;
        }
        const int pr = sp >> 1;
        u16* pw = (u16*)(pr == 0 ? (u32*)out : (pr == 1 ? pp1 : (pr == 2 ? pp2 : pp3)));
        const int hs = sp & 1;
        #pragma unroll
        for (int ct = 0; ct < 4; ++ct)
            #pragma unroll
            for (int rg = 0; rg < 16; ++rg) {
                int c = ct * 32 + (rg & 3) + ((rg >> 2) << 3) + rbase;
                size_t elem = (size_t)(b * NC + c) * NN + nq;
                pw[(elem << 1) | hs] = f2h_u(o[ct][rg]);
            }
    }
}

// ---------------------------------------------------------------------------
// Kernel 3: merge S partials. Thread owns one (b,n) column: stats loaded once,
// 32 c-values accumulated. grid = B*N/64 blocks x 256 thr.
// ---------------------------------------------------------------------------
template <int SS>
__device__ __forceinline__ void merge_body(
    const u32* p0, const u32* p1, const u32* p2, const u32* p3,
    const float* statM, const float* statL, float* out, int b, int n, int cg)
{
    float w[SS];
    float M = -3.0e38f;
    #pragma unroll
    for (int sp = 0; sp < SS; ++sp) {
        w[sp] = statM[(sp * NB + b) * NN + n];
        M = fmaxf(M, w[sp]);
    }
    float denom = 0.f;
    #pragma unroll
    for (int sp = 0; sp < SS; ++sp) {
        float e = __expf(w[sp] - M);
        denom += e * statL[(sp * NB + b) * NN + n];
        w[sp] = e;
    }
    float inv = 1.0f / denom;
    #pragma unroll
    for (int sp = 0; sp < SS; ++sp) w[sp] *= inv;

    const u32* ps[4] = {p0, p1, p2, p3};
    #pragma unroll 4
    for (int i = 0; i < 32; ++i) {
        int c = cg * 32 + i;
        size_t elem = (size_t)(b * NC + c) * NN + n;
        float acc = 0.f;
        #pragma unroll
        for (int t = 0; t < (SS >> 1); ++t) {
            u32 v = ps[t][elem];
            acc += w[2 * t] * h2f_u(v) + w[2 * t + 1] * h2f_u(v >> 16);
        }
        out[elem] = acc;
    }
}

__global__ __launch_bounds__(256) void merge_kernel(
    const u32* __restrict__ p1, const u32* __restrict__ p2, const u32* __restrict__ p3,
    const float* __restrict__ statM, const float* __restrict__ statL,
    float* __restrict__ out, int S)
{
    const int b = blockIdx.x >> 6;
    const int n = ((blockIdx.x & 63) << 6) | (threadIdx.x & 63);
    const int cg = threadIdx.x >> 6;
    const u32* p0 = (const u32*)out;
    if (S == 8) merge_body<8>(p0, p1, p2, p3, statM, statL, out, b, n, cg);
    else        merge_body<4>(p0, p1, p2, p3, statM, statL, out, b, n, cg);
}

extern "C" void kernel_launch(void* const* d_in, const int* in_sizes, int n_in,
                              void* d_out, int out_size, void* d_ws, size_t ws_size,
                              hipStream_t stream)
{
    const float* x  = (const float*)d_in[0];
    const float* wq = (const float*)d_in[1];
    const float* bq = (const float*)d_in[2];
    const float* wk = (const float*)d_in[3];
    const float* bk = (const float*)d_in[4];
    const float* wv = (const float*)d_in[5];
    const float* bv = (const float*)d_in[6];

    const size_t TE = (size_t)NB * NN * NC;              // 2M halves / tensor
    _Float16* Qb = (_Float16*)d_ws;
    _Float16* Kb = Qb + TE;
    _Float16* Vb = Kb + TE;
    char* base = (char*)d_ws;
    const size_t statOff = 3 * TE * 2;                   // 12 MB
    const size_t statSz  = (size_t)8 * NB * NN * 4;      // 512 KB
    float* statM = (float*)(base + statOff);
    float* statL = (float*)(base + statOff + statSz);
    const size_t pOff = statOff + 2 * statSz;            // 13 MB
    const size_t pSz  = (size_t)NB * NC * NN * 4;        // 8 MB per pair
    u32* p1 = (u32*)(base + pOff);
    u32* p2 = (u32*)(base + pOff + pSz);
    u32* p3 = (u32*)(base + pOff + 2 * pSz);

    int lg2S;
    if (ws_size >= pOff + 3 * pSz)      lg2S = 3;        // S=8
    else if (ws_size >= pOff + pSz)     lg2S = 2;        // S=4
    else                                lg2S = 0;        // S=1

    qkv_proj_kernel<<<dim3(256), dim3(512), 0, stream>>>(x, wq, bq, wk, bk, wv, bv, Qb, Kb, Vb);
    attn_kernel<<<dim3(128 << lg2S), dim3(256), 0, stream>>>(Qb, Kb, Vb, (float*)d_out,
                                                             p1, p2, p3, statM, statL, lg2S);
    if (lg2S > 0)
        merge_kernel<<<dim3(NB * (NN / 64)), dim3(256), 0, stream>>>(p1, p2, p3, statM, statL,
                                                                     (float*)d_out, 1 << lg2S);
}

// Round 6
// 69.528 us; speedup vs baseline: 5.2407x; 1.1810x over previous
//
#include <hip/hip_runtime.h>

typedef _Float16 half8 __attribute__((ext_vector_type(8)));
typedef __fp16 fp16x2 __attribute__((ext_vector_type(2)));
typedef float f32x4 __attribute__((ext_vector_type(4)));
typedef float f32x16 __attribute__((ext_vector_type(16)));
typedef unsigned int u32;
typedef unsigned short u16;

#define NB 4
#define NC 128
#define NN 4096
#define THR 8.0f

__device__ __forceinline__ void gload16(const void* g, void* l) {
    __builtin_amdgcn_global_load_lds(
        (const __attribute__((address_space(1))) u32*)g,
        (__attribute__((address_space(3))) u32*)l, 16, 0, 0);
}
__device__ __forceinline__ float h2f_u(u32 u) {
    u16 us = (u16)u;
    _Float16 h;
    __builtin_memcpy(&h, &us, 2);
    return (float)h;
}
__device__ __forceinline__ u16 f2h_u(float f) {
    _Float16 h = (_Float16)f;
    u16 us;
    __builtin_memcpy(&us, &h, 2);
    return us;
}
__device__ __forceinline__ float exp2_fast(float x) {
#if __has_builtin(__builtin_amdgcn_exp2f)
    return __builtin_amdgcn_exp2f(x);
#else
    return exp2f(x);
#endif
}
__device__ __forceinline__ int xs_addr(int c, int n) {
    return ((c << 8) + (n << 2)) ^ (((c >> 3) & 1) << 6);
}

// ---------------------------------------------------------------------------
// Kernel 1: QKV projection via fp16 MFMA (unchanged; works).
// ---------------------------------------------------------------------------
__global__ __launch_bounds__(512, 2) void qkv_proj_kernel(
    const float* __restrict__ x,
    const float* __restrict__ wq, const float* __restrict__ bq,
    const float* __restrict__ wk, const float* __restrict__ bk,
    const float* __restrict__ wv, const float* __restrict__ bv,
    _Float16* __restrict__ Qb, _Float16* __restrict__ Kb, _Float16* __restrict__ Vt)
{
    const int tid  = threadIdx.x;
    const int b    = blockIdx.x >> 6;
    const int n0   = (blockIdx.x & 63) << 6;
    const int lane = tid & 63;
    const int wave = __builtin_amdgcn_readfirstlane(tid >> 6);
    const int l15  = lane & 15, lg = lane >> 4;
    const int obase = wave * 16;

    __shared__ __align__(16) unsigned char xsm[32768];

    #pragma unroll
    for (int kk = 0; kk < 4; ++kk) {
        int g = kk * 512 + tid;
        int c = g >> 4, n4 = (g & 15) << 2;
        *(float4*)(xsm + xs_addr(c, n4)) = *(const float4*)(x + (size_t)(b * NC + c) * NN + n0 + n4);
    }
    __syncthreads();

    half8 bx[4][4];
    #pragma unroll
    for (int ct2 = 0; ct2 < 4; ++ct2) {
        int n = ct2 * 16 + l15;
        #pragma unroll
        for (int kc = 0; kc < 4; ++kc) {
            half8 h;
            #pragma unroll
            for (int j = 0; j < 8; ++j) {
                int c = kc * 32 + lg * 8 + j;
                h[j] = (_Float16)(*(const float*)(xsm + xs_addr(c, n)));
            }
            bx[ct2][kc] = h;
        }
    }

    #pragma unroll 1
    for (int mat = 0; mat < 3; ++mat) {
        const float* __restrict__ W  = (mat == 0) ? wq : ((mat == 1) ? wk : wv);
        const float* __restrict__ bi = (mat == 0) ? bq : ((mat == 1) ? bk : bv);

        half8 aw[4];
        #pragma unroll
        for (int kc = 0; kc < 4; ++kc) {
            const float* wp = W + (size_t)(obase + l15) * NC + kc * 32 + lg * 8;
            float4 w0 = *(const float4*)(wp);
            float4 w1 = *(const float4*)(wp + 4);
            half8 h;
            h[0] = (_Float16)w0.x; h[1] = (_Float16)w0.y; h[2] = (_Float16)w0.z; h[3] = (_Float16)w0.w;
            h[4] = (_Float16)w1.x; h[5] = (_Float16)w1.y; h[6] = (_Float16)w1.z; h[7] = (_Float16)w1.w;
            aw[kc] = h;
        }
        float bvv[4];
        #pragma unroll
        for (int r = 0; r < 4; ++r) bvv[r] = bi[obase + lg * 4 + r];

        f32x4 acc[4];
        #pragma unroll
        for (int ct2 = 0; ct2 < 4; ++ct2) acc[ct2] = (f32x4){0.f, 0.f, 0.f, 0.f};
        #pragma unroll
        for (int kc = 0; kc < 4; ++kc) {
            #pragma unroll
            for (int ct2 = 0; ct2 < 4; ++ct2)
                acc[ct2] = __builtin_amdgcn_mfma_f32_16x16x32_f16(aw[kc], bx[ct2][kc], acc[ct2], 0, 0, 0);
        }

        if (mat < 2) {
            _Float16* dst = (mat == 0) ? Qb : Kb;
            #pragma unroll
            for (int ct2 = 0; ct2 < 4; ++ct2) {
                int n = n0 + ct2 * 16 + l15;
                #pragma unroll
                for (int r = 0; r < 4; ++r)
                    dst[(size_t)(b * NN + n) * NC + obase + lg * 4 + r] = (_Float16)(acc[ct2][r] + bvv[r]);
            }
        } else {
            #pragma unroll
            for (int ct2 = 0; ct2 < 4; ++ct2) {
                int n = n0 + ct2 * 16 + l15;
                #pragma unroll
                for (int r = 0; r < 4; ++r)
                    Vt[(size_t)(b * NC + obase + lg * 4 + r) * NN + n] = (_Float16)(acc[ct2][r] + bvv[r]);
            }
        }
    }
}

// ---------------------------------------------------------------------------
// Kernel 2: flash attention, 32x32x16 MFMA, double-buffered LDS (64KB),
// counted-vmcnt pipeline with raw s_barrier (loads stay in flight across
// barriers). kv-split S=4; partials normalized per-split, stored as
// contiguous fp16 tensors (coalesced). Defer-rescale THR=8, exp2-domain.
// ---------------------------------------------------------------------------
__global__ __launch_bounds__(256, 2) void attn_kernel(
    const _Float16* __restrict__ Qb, const _Float16* __restrict__ Kb,
    const _Float16* __restrict__ Vt, float* __restrict__ out,
    u16* __restrict__ parts, float* __restrict__ statM, float* __restrict__ statL,
    int lg2S)
{
    const int S = 1 << lg2S;
    const int tid = threadIdx.x;
    const int cpx = gridDim.x >> 3;
    const int lin = (blockIdx.x & 7) * cpx + (blockIdx.x >> 3);
    const int qt   = lin & 31;
    const int rest = lin >> 5;             // = b * S + sp
    const int sp = rest & (S - 1);
    const int b  = rest >> lg2S;

    const int n0    = qt << 7;             // 128 q per block
    const int kvlen = NN >> lg2S;
    const int kv0   = sp * kvlen;
    const int iters = kvlen >> 6;

    const int lane = tid & 63;
    const int wave = __builtin_amdgcn_readfirstlane(tid >> 6);
    const int l31 = lane & 31, hi = lane >> 5;
    const int s7 = l31 & 7;

    // double buffer: buf = (it&1)<<15. Within buf: K [0,16K), V [16K,32K).
    __shared__ __align__(16) unsigned char smem[65536];

    // ---- staging source offsets (linear LDS dest; inverse of layout map) ----
    int kgo[4], vgo[4], klds[4];
    #pragma unroll
    for (int j = 0; j < 4; ++j) {
        int i = (wave * 4 + j) * 64 + lane;          // chunk 0..1023 (16B units)
        int lam = i >> 4, slot = i & 15;
        int cc = (slot & 8) | ((slot & 7) ^ (lam & 7));
        int kv = (lam & 51) | ((lam & 4) << 1) | ((lam & 8) >> 1);  // swap bits 2,3
        kgo[j] = kv * NC + cc * 8;
        int c = i >> 3, s2 = i & 7;
        vgo[j] = c * NN + ((s2 ^ (c & 7)) << 3);
        klds[j] = (wave * 4 + j) * 1024;
    }
    const _Float16* Kt0 = Kb + ((size_t)b * NN + kv0) * NC;
    const _Float16* Vt0 = Vt + (size_t)b * NC * NN + kv0;

    // ---- fragment read offsets ----
    int koff[8];
    #pragma unroll
    for (int kc = 0; kc < 8; ++kc) {
        int cc = kc * 2 + hi;
        koff[kc] = l31 * 256 + (((cc & 8) | ((cc & 7) ^ s7)) << 4);
    }
    int voff[4];
    #pragma unroll
    for (int ks = 0; ks < 4; ++ks) {
        int cc2 = ks * 2 + hi;
        voff[ks] = 16384 + l31 * 128 + ((cc2 ^ s7) << 4);
    }

    auto STAGE = [&](int t, int bb) {
        const _Float16* Kp = Kt0 + (size_t)t * 64 * NC;
        const _Float16* Vp = Vt0 + t * 64;
        #pragma unroll
        for (int j = 0; j < 4; ++j) {
            gload16(Kp + kgo[j], smem + bb + klds[j]);
            gload16(Vp + vgo[j], smem + bb + 16384 + klds[j]);
        }
    };

    // ---- prologue: Q frags first (oldest vmem), then tiles 0 and 1 ----
    half8 aq[8];
    {
        const _Float16* qp = Qb + (size_t)(b * NN + n0 + wave * 32 + l31) * NC + hi * 8;
        #pragma unroll
        for (int kc = 0; kc < 8; ++kc) aq[kc] = *(const half8*)(qp + kc * 16);
    }
    STAGE(0, 0);
    if (iters > 1) {
        STAGE(1, 32768);
        asm volatile("s_waitcnt vmcnt(8)" ::: "memory");  // aq + tile0 landed; tile1 in flight
    } else {
        asm volatile("s_waitcnt vmcnt(0)" ::: "memory");
    }
    __builtin_amdgcn_s_barrier();

    float mrun = -3.0e38f, lsum = 0.f;
    f32x16 o[4];
    #pragma unroll
    for (int ct = 0; ct < 4; ++ct)
        #pragma unroll
        for (int r = 0; r < 16; ++r) o[ct][r] = 0.f;

    const float L2E = 1.44269504f;

    for (int it = 0; it < iters; ++it) {
        const int bb = (it & 1) << 15;

        // ---- S = K Q^T : D[lds-row][q=l31] ----
        f32x16 s0, s1;
        #pragma unroll
        for (int r = 0; r < 16; ++r) { s0[r] = 0.f; s1[r] = 0.f; }
        __builtin_amdgcn_s_setprio(1);
        #pragma unroll
        for (int kc = 0; kc < 8; ++kc) {
            half8 k0 = *(const half8*)(smem + bb + koff[kc]);
            half8 k1 = *(const half8*)(smem + bb + koff[kc] + 8192);
            s0 = __builtin_amdgcn_mfma_f32_32x32x16_f16(k0, aq[kc], s0, 0, 0, 0);
            s1 = __builtin_amdgcn_mfma_f32_32x32x16_f16(k1, aq[kc], s1, 0, 0, 0);
        }
        __builtin_amdgcn_s_setprio(0);

        // ---- online softmax, in-lane for q = l31; defer-rescale THR ----
        float tm = fmaxf(s0[0], s0[1]);
        #pragma unroll
        for (int r = 2; r < 16; r += 2) tm = fmaxf(tm, fmaxf(s0[r], s0[r + 1]));
        #pragma unroll
        for (int r = 0; r < 16; r += 2) tm = fmaxf(tm, fmaxf(s1[r], s1[r + 1]));
        tm = fmaxf(tm, __shfl_xor(tm, 32, 64));

        if (__any(tm > mrun + THR)) {
            float mnew = fmaxf(mrun, tm);
            float sc = __expf(mrun - mnew);    // first iter: exp(-inf) = 0
            #pragma unroll
            for (int ct = 0; ct < 4; ++ct)
                #pragma unroll
                for (int r = 0; r < 16; ++r) o[ct][r] *= sc;
            lsum *= sc;
            mrun = mnew;
        }
        float nm = -mrun * L2E;
        float psum = 0.f;
        #pragma unroll
        for (int r = 0; r < 16; ++r) {
            s0[r] = exp2_fast(fmaf(s0[r], L2E, nm));
            s1[r] = exp2_fast(fmaf(s1[r], L2E, nm));
            psum += s0[r] + s1[r];
        }
        psum += __shfl_xor(psum, 32, 64);
        lsum += psum;

        // ---- P -> A-frags, fully in-lane ----
        union H8 { fp16x2 h2[4]; half8 h8; };
        half8 pa[4];
        {
            H8 u0, u1, u2, u3;
            #pragma unroll
            for (int t = 0; t < 4; ++t) {
                u0.h2[t] = __builtin_amdgcn_cvt_pkrtz(s0[2 * t],     s0[2 * t + 1]);
                u1.h2[t] = __builtin_amdgcn_cvt_pkrtz(s0[8 + 2 * t], s0[9 + 2 * t]);
                u2.h2[t] = __builtin_amdgcn_cvt_pkrtz(s1[2 * t],     s1[2 * t + 1]);
                u3.h2[t] = __builtin_amdgcn_cvt_pkrtz(s1[8 + 2 * t], s1[9 + 2 * t]);
            }
            pa[0] = u0.h8; pa[1] = u1.h8; pa[2] = u2.h8; pa[3] = u3.h8;
        }

        // ---- O += V^T P : D[c][q=l31] ----
        __builtin_amdgcn_s_setprio(1);
        #pragma unroll
        for (int ks = 0; ks < 4; ++ks) {
            #pragma unroll
            for (int ct = 0; ct < 4; ++ct) {
                half8 vf = *(const half8*)(smem + bb + voff[ks] + ct * 4096);
                o[ct] = __builtin_amdgcn_mfma_f32_32x32x16_f16(vf, pa[ks], o[ct], 0, 0, 0);
            }
        }
        __builtin_amdgcn_s_setprio(0);

        asm volatile("" ::: "memory");
        __builtin_amdgcn_s_barrier();          // all waves done reading buf bb
        if (it + 2 < iters) {
            STAGE(it + 2, bb);                 // overwrite just-freed buffer
            asm volatile("s_waitcnt vmcnt(8)" ::: "memory");  // tile it+1 landed
            asm volatile("" ::: "memory");
            __builtin_amdgcn_s_barrier();      // visibility of tile it+1
        } else if (it + 1 < iters) {
            asm volatile("s_waitcnt vmcnt(0)" ::: "memory");
            __builtin_amdgcn_s_barrier();
        }
    }

    // ---- epilogue (all q-column-local); partials normalized per split ----
    const int nq = n0 + wave * 32 + l31;
    const int rbase = 4 * hi;
    float inv = 1.0f / lsum;
    if (lg2S == 0) {
        #pragma unroll
        for (int ct = 0; ct < 4; ++ct)
            #pragma unroll
            for (int rg = 0; rg < 16; ++rg) {
                int c = ct * 32 + (rg & 3) + ((rg >> 2) << 3) + rbase;
                out[(size_t)(b * NC + c) * NN + nq] = o[ct][rg] * inv;
            }
    } else {
        if (hi == 0) {
            statM[(sp * NB + b) * NN + nq] = mrun;
            statL[(sp * NB + b) * NN + nq] = lsum;
        }
        const size_t pbase = (size_t)sp * ((size_t)NB * NC * NN) + (size_t)b * NC * NN + nq;
        #pragma unroll
        for (int ct = 0; ct < 4; ++ct)
            #pragma unroll
            for (int rg = 0; rg < 16; ++rg) {
                int c = ct * 32 + (rg & 3) + ((rg >> 2) << 3) + rbase;
                parts[pbase + (size_t)c * NN] = f2h_u(o[ct][rg] * inv);
            }
    }
}

// ---------------------------------------------------------------------------
// Kernel 3: merge 4 normalized partials. grid NB*64, block 256.
// Thread owns (b, n-pair, 16 c's); weights = e^{m-M} * l, normalized.
// ---------------------------------------------------------------------------
__global__ __launch_bounds__(256) void merge_kernel(
    const u16* __restrict__ parts,
    const float* __restrict__ statM, const float* __restrict__ statL,
    float* __restrict__ out)
{
    const int b  = blockIdx.x >> 6;
    const int nb = (blockIdx.x & 63) << 6;
    const int t  = threadIdx.x;
    const int n  = nb + ((t & 31) << 1);
    const int cg = t >> 5;
    const size_t PST = (size_t)NB * NC * NN;

    float w0[4], w1[4];
    {
        float M0 = -3.0e38f, M1 = -3.0e38f;
        #pragma unroll
        for (int sp = 0; sp < 4; ++sp) {
            w0[sp] = statM[(sp * NB + b) * NN + n];
            w1[sp] = statM[(sp * NB + b) * NN + n + 1];
            M0 = fmaxf(M0, w0[sp]); M1 = fmaxf(M1, w1[sp]);
        }
        float d0 = 0.f, d1 = 0.f;
        #pragma unroll
        for (int sp = 0; sp < 4; ++sp) {
            float e0 = __expf(w0[sp] - M0) * statL[(sp * NB + b) * NN + n];
            float e1 = __expf(w1[sp] - M1) * statL[(sp * NB + b) * NN + n + 1];
            w0[sp] = e0; w1[sp] = e1; d0 += e0; d1 += e1;
        }
        d0 = 1.f / d0; d1 = 1.f / d1;
        #pragma unroll
        for (int sp = 0; sp < 4; ++sp) { w0[sp] *= d0; w1[sp] *= d1; }
    }

    #pragma unroll 4
    for (int i = 0; i < 16; ++i) {
        int c = cg * 16 + i;
        size_t e = (size_t)(b * NC + c) * NN + n;
        float a0 = 0.f, a1 = 0.f;
        #pragma unroll
        for (int sp = 0; sp < 4; ++sp) {
            u32 v = *(const u32*)(parts + sp * PST + e);
            a0 += w0[sp] * h2f_u(v);
            a1 += w1[sp] * h2f_u(v >> 16);
        }
        float2 r; r.x = a0; r.y = a1;
        *(float2*)(out + e) = r;
    }
}

extern "C" void kernel_launch(void* const* d_in, const int* in_sizes, int n_in,
                              void* d_out, int out_size, void* d_ws, size_t ws_size,
                              hipStream_t stream)
{
    const float* x  = (const float*)d_in[0];
    const float* wq = (const float*)d_in[1];
    const float* bq = (const float*)d_in[2];
    const float* wk = (const float*)d_in[3];
    const float* bk = (const float*)d_in[4];
    const float* wv = (const float*)d_in[5];
    const float* bv = (const float*)d_in[6];

    const size_t TE = (size_t)NB * NN * NC;              // 2M elems / tensor
    _Float16* Qb = (_Float16*)d_ws;
    _Float16* Kb = Qb + TE;
    _Float16* Vb = Kb + TE;
    char* base = (char*)d_ws;
    const size_t statOff = 3 * TE * 2;                   // 12 MB
    const size_t statSz  = (size_t)4 * NB * NN * 4;      // 256 KB (S=4)
    float* statM = (float*)(base + statOff);
    float* statL = (float*)(base + statOff + statSz);
    const size_t pOff = statOff + 2 * statSz;
    u16* parts = (u16*)(base + pOff);
    const size_t need = pOff + 4 * TE * 2;               // + 16 MB partials

    int lg2S = (ws_size >= need) ? 2 : 0;                // S=4 or fallback S=1

    qkv_proj_kernel<<<dim3(256), dim3(512), 0, stream>>>(x, wq, bq, wk, bk, wv, bv, Qb, Kb, Vb);
    attn_kernel<<<dim3(128 << lg2S), dim3(256), 0, stream>>>(Qb, Kb, Vb, (float*)d_out,
                                                             parts, statM, statL, lg2S);
    if (lg2S > 0)
        merge_kernel<<<dim3(NB * 64), dim3(256), 0, stream>>>(parts, statM, statL, (float*)d_out);
}